// Round 3
// baseline (1217.117 us; speedup 1.0000x reference)
//
#include <hip/hip_runtime.h>

#define T_TOK 1024
#define D_HID 2048
#define NEXP 32
#define I_EXP 1408
#define TOPK 6
#define NGRP 8
#define GSIZE 4
#define TOPG 3
#define SHI 2816
#define RSCALE 2.5f

typedef __attribute__((ext_vector_type(8))) short short8;
typedef __attribute__((ext_vector_type(4))) float floatx4;

__device__ __forceinline__ unsigned short f2b(float f) {
  unsigned int u = __float_as_uint(f);
  u += 0x7fffu + ((u >> 16) & 1u);   // RNE
  return (unsigned short)(u >> 16);
}

__device__ __forceinline__ void gld_lds16(const void* g, void* l) {
  __builtin_amdgcn_global_load_lds(
      (const __attribute__((address_space(1))) unsigned int*)g,
      (__attribute__((address_space(3))) unsigned int*)l, 16, 0, 0);
}

// ---------------- routing: one block (1 wave) per token ----------------
__global__ __launch_bounds__(64) void k_route(
    const float* __restrict__ x, const float* __restrict__ gw,
    const float* __restrict__ bias, int* __restrict__ tki, float* __restrict__ tkw)
{
  int t = blockIdx.x;
  __shared__ float xs[D_HID];
  __shared__ float sc[NEXP], cor[NEXP];
  int lane = threadIdx.x;
  for (int d = lane * 4; d < D_HID; d += 64 * 4)
    *(float4*)(xs + d) = *(const float4*)(x + (size_t)t * D_HID + d);
  __syncthreads();
  if (lane < NEXP) {
    float acc = 0.f;
    for (int d = 0; d < D_HID; ++d) acc += xs[d] * gw[d * NEXP + lane];
    float s = 1.f / (1.f + expf(-acc));
    sc[lane] = s;
    cor[lane] = s + bias[lane];
  }
  __syncthreads();
  if (lane == 0) {
    float gs[NGRP];
    for (int g = 0; g < NGRP; ++g) {
      float m1 = -INFINITY, m2 = -INFINITY;
      for (int j = 0; j < GSIZE; ++j) {
        float v = cor[g * GSIZE + j];
        if (v > m1) { m2 = m1; m1 = v; } else if (v > m2) m2 = v;
      }
      gs[g] = m1 + m2;
    }
    unsigned gmask = 0;
    for (int r = 0; r < TOPG; ++r) {
      int bi = -1; float bv = -INFINITY;
      for (int g = 0; g < NGRP; ++g)
        if (!((gmask >> g) & 1) && gs[g] > bv) { bv = gs[g]; bi = g; }
      gmask |= 1u << bi;
    }
    unsigned used = 0;
    float wsum = 0.f;
    int idxs[TOPK]; float wsel[TOPK];
    for (int r = 0; r < TOPK; ++r) {
      int bi = -1; float bv = -INFINITY;
      for (int e = 0; e < NEXP; ++e) {
        if (!((gmask >> (e / GSIZE)) & 1)) continue;
        if ((used >> e) & 1) continue;
        if (cor[e] > bv) { bv = cor[e]; bi = e; }
      }
      used |= 1u << bi;
      idxs[r] = bi; wsel[r] = sc[bi]; wsum += sc[bi];
    }
    float inv = 1.f / (wsum + 1e-20f);
    for (int r = 0; r < TOPK; ++r) {
      tki[t * TOPK + r] = idxs[r];
      tkw[t * TOPK + r] = wsel[r] * inv;
    }
  }
}

// ---------------- counts + offsets (single block) ----------------
__global__ __launch_bounds__(256) void k_count(const int* __restrict__ tki,
                                               int* __restrict__ cnt, int* __restrict__ offp)
{
  __shared__ int c[NEXP];
  if (threadIdx.x < NEXP) c[threadIdx.x] = 0;
  __syncthreads();
  for (int i = threadIdx.x; i < T_TOK * TOPK; i += 256) atomicAdd(&c[tki[i]], 1);
  __syncthreads();
  if (threadIdx.x == 0) {
    int s = 0;
    for (int e = 0; e < NEXP; ++e) { offp[e] = s; cnt[e] = c[e]; s += c[e]; }
    offp[NEXP] = s;
  }
}

// ---------------- deterministic compaction: one wave per expert ----------------
__global__ __launch_bounds__(64) void k_compact(
    const int* __restrict__ tki, const float* __restrict__ tkw,
    const int* __restrict__ offp, int* __restrict__ tok, float* __restrict__ wts)
{
  int e = blockIdx.x, lane = threadIdx.x;
  int base = offp[e];
  for (int t0 = 0; t0 < T_TOK; t0 += 64) {
    int t = t0 + lane;
    int found = -1;
    for (int j = 0; j < TOPK; ++j)
      if (tki[t * TOPK + j] == e) found = j;
    unsigned long long m = __ballot(found >= 0);
    if (found >= 0) {
      int pos = base + __popcll(m & ((1ull << lane) - 1ull));
      tok[pos] = t;
      wts[pos] = tkw[t * TOPK + found];
    }
    base += __popcll(m);
  }
}

// ---------------- fp32 -> bf16 cast of hidden states ----------------
__global__ __launch_bounds__(256) void k_cast(const float* __restrict__ x,
                                              unsigned short* __restrict__ xb, int n4)
{
  int i = blockIdx.x * 256 + threadIdx.x;
  if (i < n4) {
    float4 v = ((const float4*)x)[i];
    ushort4 o;
    o.x = f2b(v.x); o.y = f2b(v.y); o.z = f2b(v.z); o.w = f2b(v.w);
    ((ushort4*)xb)[i] = o;
  }
}

// =================================================================
// Gate+Up fused grouped GEMM.  512 thr (8 waves), tile 256m x 64n, BK=32,
// double-buffered LDS, depth-1 prefetch.
// A LDS layout: 16B granules [kk][m] (conflict-free reads, linear gld_lds dest).
// B LDS layout: [n][k] pad 40, staged via per-thread k-run (8 scalar loads ->
// one ds_write_b128; conflict-free).  Waves 0-3 stage gate, 4-7 stage up.
// =================================================================
__global__ __launch_bounds__(512) void k_gateup2(
    const unsigned short* __restrict__ xb,
    const float* __restrict__ wg_base, const float* __restrict__ wu_base,
    const int* __restrict__ offp, const int* __restrict__ cnt,
    const int* __restrict__ tok,
    unsigned short* __restrict__ hout,
    int N, int K)
{
  __shared__ __align__(16) unsigned short As[2][1024 * 8];  // 1024 granules x 16B
  __shared__ __align__(16) unsigned short Bg[2][64][40];
  __shared__ __align__(16) unsigned short Bu[2][64][40];

  int tid = threadIdx.x;
  int wid = tid >> 6, lane = tid & 63;
  int n0 = blockIdx.x * 64;

  int e, rowbase, nrows;
  if (offp) { e = blockIdx.y; rowbase = offp[e]; nrows = cnt[e]; }
  else      { e = 0; rowbase = blockIdx.y * 256; nrows = 256; }

  const float* wg = wg_base + (size_t)e * K * N;
  const float* wu = wu_base + (size_t)e * K * N;

  // B staging mapping: thread -> (mat, k-octet bko, col bn)
  int bn  = tid & 63;
  int bko = (tid >> 6) & 3;
  bool isUp = (tid >= 256);
  const float* bsrc = (isUp ? wu : wg) + (size_t)(bko * 8) * N + n0 + bn;

  // A staging: thread stages granules (m = tid&255, kk = tid>>8) and (kk+2)
  int am  = tid & 255;
  int ak  = (tid >> 8) * 8;     // element offset of first granule's k-octet
  int NK = K / 32;

  for (int m0 = 0; m0 < nrows; m0 += 256) {
    const unsigned short* arow;
    if (offp) {
      int tA = tok[rowbase + min(m0 + am, nrows - 1)];
      arow = xb + (size_t)tA * K;
    } else {
      arow = xb + (size_t)(rowbase + am) * K;
    }

    floatx4 accg[2][4] = {};
    floatx4 accu[2][4] = {};

    // prologue: stage tile 0 into buf 0
    gld_lds16(arow + ak, &As[0][tid * 8]);
    gld_lds16(arow + 16 + ak, &As[0][(512 + tid) * 8]);
    {
      alignas(16) unsigned short bt[8];
      #pragma unroll
      for (int j = 0; j < 8; ++j) bt[j] = f2b(bsrc[(size_t)j * N]);
      unsigned short* dst = isUp ? &Bu[0][bn][bko * 8] : &Bg[0][bn][bko * 8];
      *(uint4*)dst = *(const uint4*)bt;
    }
    __syncthreads();

    int b = 0;
    for (int kt = 0; kt < NK; ++kt) {
      float br[8];
      bool pre = (kt + 1 < NK);
      if (pre) {
        int k1 = (kt + 1) * 32;
        gld_lds16(arow + k1 + ak, &As[b ^ 1][tid * 8]);
        gld_lds16(arow + k1 + 16 + ak, &As[b ^ 1][(512 + tid) * 8]);
        #pragma unroll
        for (int j = 0; j < 8; ++j) br[j] = bsrc[(size_t)(k1 + j) * N];
      }
      // compute current buffer
      {
        int koff = lane >> 4;
        short8 af0 = *(const short8*)&As[b][(koff * 256 + wid * 32 + (lane & 15)) * 8];
        short8 af1 = *(const short8*)&As[b][(koff * 256 + wid * 32 + 16 + (lane & 15)) * 8];
        #pragma unroll
        for (int nf = 0; nf < 4; ++nf) {
          short8 bg = *(const short8*)&Bg[b][nf * 16 + (lane & 15)][koff * 8];
          accg[0][nf] = __builtin_amdgcn_mfma_f32_16x16x32_bf16(af0, bg, accg[0][nf], 0, 0, 0);
          accg[1][nf] = __builtin_amdgcn_mfma_f32_16x16x32_bf16(af1, bg, accg[1][nf], 0, 0, 0);
          short8 bu = *(const short8*)&Bu[b][nf * 16 + (lane & 15)][koff * 8];
          accu[0][nf] = __builtin_amdgcn_mfma_f32_16x16x32_bf16(af0, bu, accu[0][nf], 0, 0, 0);
          accu[1][nf] = __builtin_amdgcn_mfma_f32_16x16x32_bf16(af1, bu, accu[1][nf], 0, 0, 0);
        }
      }
      if (pre) {
        alignas(16) unsigned short bt[8];
        #pragma unroll
        for (int j = 0; j < 8; ++j) bt[j] = f2b(br[j]);
        unsigned short* dst = isUp ? &Bu[b ^ 1][bn][bko * 8] : &Bg[b ^ 1][bn][bko * 8];
        *(uint4*)dst = *(const uint4*)bt;
      }
      __syncthreads();
      b ^= 1;
    }

    // epilogue: silu(g)*u -> bf16
    #pragma unroll
    for (int mi = 0; mi < 2; ++mi)
      #pragma unroll
      for (int nf = 0; nf < 4; ++nf)
        #pragma unroll
        for (int v = 0; v < 4; ++v) {
          int r = wid * 32 + mi * 16 + (lane >> 4) * 4 + v;
          if (m0 + r < nrows) {
            float g = accg[mi][nf][v], u = accu[mi][nf][v];
            float s = g / (1.f + __expf(-g));
            hout[(size_t)(rowbase + m0 + r) * N + n0 + nf * 16 + (lane & 15)] = f2b(s * u);
          }
        }
  }
}

// =================================================================
// Down-proj grouped GEMM.  Same structure, single B mat (ds_write_b64 staging).
// Routed: atomicAdd(w*scale*acc) scattered by token.  Dense: plain store.
// =================================================================
__global__ __launch_bounds__(512) void k_down2(
    const unsigned short* __restrict__ hin,
    const float* __restrict__ wd_base,
    const int* __restrict__ offp, const int* __restrict__ cnt,
    const int* __restrict__ tok, const float* __restrict__ wts,
    float* __restrict__ out,
    int N, int K, float scale)
{
  __shared__ __align__(16) unsigned short As[2][1024 * 8];
  __shared__ __align__(16) unsigned short Bd[2][64][40];

  int tid = threadIdx.x;
  int wid = tid >> 6, lane = tid & 63;
  int n0 = blockIdx.x * 64;

  int e, rowbase, nrows;
  if (offp) { e = blockIdx.y; rowbase = offp[e]; nrows = cnt[e]; }
  else      { e = 0; rowbase = blockIdx.y * 256; nrows = 256; }

  const float* wd = wd_base + (size_t)e * K * N;

  // B staging: thread -> (col bn, k-octet bko, half bh): 4 scalar loads -> b64
  int bn  = tid & 63;
  int bko = (tid >> 6) & 3;
  int bh  = tid >> 8;           // 0/1
  const float* bsrc = wd + (size_t)(bko * 8 + bh * 4) * N + n0 + bn;

  int am = tid & 255;
  int ak = (tid >> 8) * 8;
  int NK = K / 32;

  for (int m0 = 0; m0 < nrows; m0 += 256) {
    int rl = rowbase + (offp ? min(m0 + am, nrows - 1) : (m0 + am));
    const unsigned short* arow = hin + (size_t)rl * K;

    floatx4 acc[2][4] = {};

    gld_lds16(arow + ak, &As[0][tid * 8]);
    gld_lds16(arow + 16 + ak, &As[0][(512 + tid) * 8]);
    {
      alignas(8) unsigned short bt[4];
      #pragma unroll
      for (int j = 0; j < 4; ++j) bt[j] = f2b(bsrc[(size_t)j * N]);
      *(uint2*)&Bd[0][bn][bko * 8 + bh * 4] = *(const uint2*)bt;
    }
    __syncthreads();

    int b = 0;
    for (int kt = 0; kt < NK; ++kt) {
      float br[4];
      bool pre = (kt + 1 < NK);
      if (pre) {
        int k1 = (kt + 1) * 32;
        gld_lds16(arow + k1 + ak, &As[b ^ 1][tid * 8]);
        gld_lds16(arow + k1 + 16 + ak, &As[b ^ 1][(512 + tid) * 8]);
        #pragma unroll
        for (int j = 0; j < 4; ++j) br[j] = bsrc[(size_t)(k1 + j) * N];
      }
      {
        int koff = lane >> 4;
        short8 af0 = *(const short8*)&As[b][(koff * 256 + wid * 32 + (lane & 15)) * 8];
        short8 af1 = *(const short8*)&As[b][(koff * 256 + wid * 32 + 16 + (lane & 15)) * 8];
        #pragma unroll
        for (int nf = 0; nf < 4; ++nf) {
          short8 bd = *(const short8*)&Bd[b][nf * 16 + (lane & 15)][koff * 8];
          acc[0][nf] = __builtin_amdgcn_mfma_f32_16x16x32_bf16(af0, bd, acc[0][nf], 0, 0, 0);
          acc[1][nf] = __builtin_amdgcn_mfma_f32_16x16x32_bf16(af1, bd, acc[1][nf], 0, 0, 0);
        }
      }
      if (pre) {
        alignas(8) unsigned short bt[4];
        #pragma unroll
        for (int j = 0; j < 4; ++j) bt[j] = f2b(br[j]);
        *(uint2*)&Bd[b ^ 1][bn][bko * 8 + bh * 4] = *(const uint2*)bt;
      }
      __syncthreads();
      b ^= 1;
    }

    #pragma unroll
    for (int mi = 0; mi < 2; ++mi)
      #pragma unroll
      for (int nf = 0; nf < 4; ++nf)
        #pragma unroll
        for (int v = 0; v < 4; ++v) {
          int r = wid * 32 + mi * 16 + (lane >> 4) * 4 + v;
          if (m0 + r < nrows) {
            int grow = rowbase + m0 + r;
            int col = n0 + nf * 16 + (lane & 15);
            if (offp) {
              float w = wts[grow] * scale;
              atomicAdd(&out[(size_t)tok[grow] * N + col], w * acc[mi][nf][v]);
            } else {
              out[(size_t)grow * N + col] = acc[mi][nf][v] * scale;
            }
          }
        }
  }
}

extern "C" void kernel_launch(void* const* d_in, const int* in_sizes, int n_in,
                              void* d_out, int out_size, void* d_ws, size_t ws_size,
                              hipStream_t stream) {
  const float* x    = (const float*)d_in[0];
  const float* gw   = (const float*)d_in[1];
  const float* bias = (const float*)d_in[2];
  const float* wg   = (const float*)d_in[3];
  const float* wu   = (const float*)d_in[4];
  const float* wd   = (const float*)d_in[5];
  const float* wsg  = (const float*)d_in[6];
  const float* wsu  = (const float*)d_in[7];
  const float* wsd  = (const float*)d_in[8];
  float* out = (float*)d_out;

  char* ws = (char*)d_ws;
  size_t o = 0;
  auto take = [&](size_t bytes) {
    char* p = ws + o;
    o += (bytes + 255) & ~(size_t)255;
    return p;
  };
  int*   tki  = (int*)  take((size_t)T_TOK * TOPK * 4);
  float* tkw  = (float*)take((size_t)T_TOK * TOPK * 4);
  int*   cnt  = (int*)  take(NEXP * 4);
  int*   offp = (int*)  take((NEXP + 1) * 4);
  int*   tok  = (int*)  take((size_t)T_TOK * TOPK * 4);
  float* wts  = (float*)take((size_t)T_TOK * TOPK * 4);
  unsigned short* xb = (unsigned short*)take((size_t)T_TOK * D_HID * 2);
  unsigned short* hb = (unsigned short*)take((size_t)T_TOK * TOPK * I_EXP * 2);
  unsigned short* sh = (unsigned short*)take((size_t)T_TOK * SHI * 2);

  k_route<<<T_TOK, 64, 0, stream>>>(x, gw, bias, tki, tkw);
  k_count<<<1, 256, 0, stream>>>(tki, cnt, offp);
  k_compact<<<NEXP, 64, 0, stream>>>(tki, tkw, offp, tok, wts);
  k_cast<<<(T_TOK * D_HID / 4 + 255) / 256, 256, 0, stream>>>(x, xb, T_TOK * D_HID / 4);

  // shared expert gate+up (dense, 4 m-chunks)
  k_gateup2<<<dim3(SHI / 64, T_TOK / 256), 512, 0, stream>>>(
      xb, wsg, wsu, nullptr, nullptr, nullptr, sh, SHI, D_HID);
  // routed gate+up (grouped, in-kernel m loop)
  k_gateup2<<<dim3(I_EXP / 64, NEXP), 512, 0, stream>>>(
      xb, wg, wu, offp, cnt, tok, hb, I_EXP, D_HID);
  // shared down: plain store (initializes out, replaces memset)
  k_down2<<<dim3(D_HID / 64, T_TOK / 256), 512, 0, stream>>>(
      sh, wsd, nullptr, nullptr, nullptr, nullptr, out, D_HID, SHI, 1.0f);
  // routed down: atomic accumulate on top
  k_down2<<<dim3(D_HID / 64, NEXP), 512, 0, stream>>>(
      hb, wd, offp, cnt, tok, wts, out, D_HID, I_EXP, RSCALE);
}

// Round 4
// 961.323 us; speedup vs baseline: 1.2661x; 1.2661x over previous
//
#include <hip/hip_runtime.h>

#define T_TOK 1024
#define D_HID 2048
#define NEXP 32
#define I_EXP 1408
#define TOPK 6
#define NGRP 8
#define GSIZE 4
#define TOPG 3
#define SHI 2816
#define RSCALE 2.5f

typedef __attribute__((ext_vector_type(8))) short short8;
typedef __attribute__((ext_vector_type(4))) float floatx4;

#define SCHED0 __builtin_amdgcn_sched_barrier(0)
#define SBAR __builtin_amdgcn_s_barrier()
#define LGKM0 asm volatile("s_waitcnt lgkmcnt(0)" ::: "memory")

__device__ __forceinline__ unsigned short f2b(float f) {
  unsigned int u = __float_as_uint(f);
  u += 0x7fffu + ((u >> 16) & 1u);   // RNE
  return (unsigned short)(u >> 16);
}

__device__ __forceinline__ void gld_lds16(const void* g, void* l) {
  __builtin_amdgcn_global_load_lds(
      (const __attribute__((address_space(1))) unsigned int*)g,
      (__attribute__((address_space(3))) unsigned int*)l, 16, 0, 0);
}

// 4x4 bf16 transpose across lanes {c, c+16, c+32, c+48}; r = lane>>4.
// In: v = 4 floats, n-quad (cols) at one k-row (row r of the 4x4).
// Out: (k0,k1),(k2,k3) bf16 pairs for column r (n = 4c + r).
__device__ __forceinline__ uint2 xpose_b(float4 v, int r) {
  unsigned wA = (unsigned)f2b(v.x) | ((unsigned)f2b(v.z) << 16);  // q=0,2
  unsigned wB = (unsigned)f2b(v.y) | ((unsigned)f2b(v.w) << 16);  // q=1,3
  bool b0 = (r & 1);
  unsigned sent = b0 ? wA : wB;
  unsigned got = __shfl_xor(sent, 16, 64);
  unsigned wA1 = b0 ? got : wA;   // (M1[r][0], M1[r][2])
  unsigned wB1 = b0 ? wB : got;   // (M1[r][1], M1[r][3])
  unsigned lo = (wA1 & 0xffffu) | (wB1 << 16);          // (M1[r][0], M1[r][1])
  unsigned hi = (wA1 >> 16) | (wB1 & 0xffff0000u);      // (M1[r][2], M1[r][3])
  bool b1 = (r & 2);
  unsigned sent2 = b1 ? lo : hi;
  unsigned got2 = __shfl_xor(sent2, 32, 64);
  uint2 o;
  o.x = b1 ? got2 : lo;
  o.y = b1 ? hi : got2;
  return o;
}

// ---------------- routing: one block (1 wave) per token ----------------
__global__ __launch_bounds__(64) void k_route(
    const float* __restrict__ x, const float* __restrict__ gw,
    const float* __restrict__ bias, int* __restrict__ tki, float* __restrict__ tkw)
{
  int t = blockIdx.x;
  __shared__ float xs[D_HID];
  __shared__ float sc[NEXP], cor[NEXP];
  int lane = threadIdx.x;
  for (int d = lane * 4; d < D_HID; d += 64 * 4)
    *(float4*)(xs + d) = *(const float4*)(x + (size_t)t * D_HID + d);
  __syncthreads();
  if (lane < NEXP) {
    float acc = 0.f;
    for (int d = 0; d < D_HID; ++d) acc += xs[d] * gw[d * NEXP + lane];
    float s = 1.f / (1.f + expf(-acc));
    sc[lane] = s;
    cor[lane] = s + bias[lane];
  }
  __syncthreads();
  if (lane == 0) {
    float gs[NGRP];
    for (int g = 0; g < NGRP; ++g) {
      float m1 = -INFINITY, m2 = -INFINITY;
      for (int j = 0; j < GSIZE; ++j) {
        float v = cor[g * GSIZE + j];
        if (v > m1) { m2 = m1; m1 = v; } else if (v > m2) m2 = v;
      }
      gs[g] = m1 + m2;
    }
    unsigned gmask = 0;
    for (int rr = 0; rr < TOPG; ++rr) {
      int bi = -1; float bv = -INFINITY;
      for (int g = 0; g < NGRP; ++g)
        if (!((gmask >> g) & 1) && gs[g] > bv) { bv = gs[g]; bi = g; }
      gmask |= 1u << bi;
    }
    unsigned used = 0;
    float wsum = 0.f;
    int idxs[TOPK]; float wsel[TOPK];
    for (int rr = 0; rr < TOPK; ++rr) {
      int bi = -1; float bv = -INFINITY;
      for (int e = 0; e < NEXP; ++e) {
        if (!((gmask >> (e / GSIZE)) & 1)) continue;
        if ((used >> e) & 1) continue;
        if (cor[e] > bv) { bv = cor[e]; bi = e; }
      }
      used |= 1u << bi;
      idxs[rr] = bi; wsel[rr] = sc[bi]; wsum += sc[bi];
    }
    float inv = 1.f / (wsum + 1e-20f);
    for (int rr = 0; rr < TOPK; ++rr) {
      tki[t * TOPK + rr] = idxs[rr];
      tkw[t * TOPK + rr] = wsel[rr] * inv;
    }
  }
}

// ---------------- counts + offsets (single block) ----------------
__global__ __launch_bounds__(256) void k_count(const int* __restrict__ tki,
                                               int* __restrict__ cnt, int* __restrict__ offp)
{
  __shared__ int c[NEXP];
  if (threadIdx.x < NEXP) c[threadIdx.x] = 0;
  __syncthreads();
  for (int i = threadIdx.x; i < T_TOK * TOPK; i += 256) atomicAdd(&c[tki[i]], 1);
  __syncthreads();
  if (threadIdx.x == 0) {
    int s = 0;
    for (int e = 0; e < NEXP; ++e) { offp[e] = s; cnt[e] = c[e]; s += c[e]; }
    offp[NEXP] = s;
  }
}

// ---------------- deterministic compaction: one wave per expert ----------------
__global__ __launch_bounds__(64) void k_compact(
    const int* __restrict__ tki, const float* __restrict__ tkw,
    const int* __restrict__ offp, int* __restrict__ tok, float* __restrict__ wts)
{
  int e = blockIdx.x, lane = threadIdx.x;
  int base = offp[e];
  for (int t0 = 0; t0 < T_TOK; t0 += 64) {
    int t = t0 + lane;
    int found = -1;
    for (int j = 0; j < TOPK; ++j)
      if (tki[t * TOPK + j] == e) found = j;
    unsigned long long m = __ballot(found >= 0);
    if (found >= 0) {
      int pos = base + __popcll(m & ((1ull << lane) - 1ull));
      tok[pos] = t;
      wts[pos] = tkw[t * TOPK + found];
    }
    base += __popcll(m);
  }
}

// ---------------- fp32 -> bf16 cast of hidden states ----------------
__global__ __launch_bounds__(256) void k_cast(const float* __restrict__ x,
                                              unsigned short* __restrict__ xb, int n4)
{
  int i = blockIdx.x * 256 + threadIdx.x;
  if (i < n4) {
    float4 v = ((const float4*)x)[i];
    ushort4 o;
    o.x = f2b(v.x); o.y = f2b(v.y); o.z = f2b(v.z); o.w = f2b(v.w);
    ((ushort4*)xb)[i] = o;
  }
}

// =================================================================
// Gate+Up fused grouped GEMM.  512 thr (8 waves, 4Mx2N wave grid),
// tile 256m x 64n, BK=32.  Deep pipeline: B depth-2 in regs (counted vmcnt
// keeps them in flight across raw s_barrier), A depth-1 via gld_lds with
// XOR-swizzled global source (conflict-free frag reads, linear LDS dest).
// B: coalesced float4 + in-wave bf16 butterfly transpose + ds_write_b64.
// =================================================================
__global__ __launch_bounds__(512, 4) void k_gateup3(
    const unsigned short* __restrict__ xb,
    const float* __restrict__ wg_base, const float* __restrict__ wu_base,
    const int* __restrict__ offp, const int* __restrict__ cnt,
    const int* __restrict__ tok,
    unsigned short* __restrict__ hout, int N, int K)
{
  __shared__ __align__(16) unsigned short As[2][8192];     // granules [m*4 + swz(koff)]
  __shared__ __align__(16) unsigned short Bg[2][64 * 40];  // [n][k] pad 40
  __shared__ __align__(16) unsigned short Bu[2][64 * 40];

  const int tid = threadIdx.x;
  const int wid = tid >> 6, lane = tid & 63;
  const int c = lane & 15, r = lane >> 4;
  const int n0 = blockIdx.x * 64;

  int e, rowbase, nrows;
  if (offp) { e = blockIdx.y; rowbase = offp[e]; nrows = cnt[e]; }
  else      { e = 0; rowbase = blockIdx.y * 256; nrows = 256; }
  if (nrows <= 0) return;

  const size_t matsz = (size_t)K * N;
  const float* gsrc = wg_base + (size_t)e * matsz + (size_t)(wid * 4 + r) * N + n0 + c * 4;
  const float* usrc = wu_base + (size_t)e * matsz + (size_t)(wid * 4 + r) * N + n0 + c * 4;
  const int bwoff = (4 * c + r) * 40 + wid * 4;   // shorts, uint2 dest

  const int am = tid >> 2;
  const int kksw = (tid & 3) ^ ((tid >> 3) & 3);  // swizzled source octet
  const int NK = K >> 5;

  const int wr = wid >> 1, wc = wid & 1;
  int aoff[4];
  #pragma unroll
  for (int mf = 0; mf < 4; ++mf) {
    int m = wr * 64 + mf * 16 + c;
    aoff[mf] = (m * 4 + (r ^ ((m >> 1) & 3))) * 8;
  }
  int boff[2];
  #pragma unroll
  for (int nf = 0; nf < 2; ++nf)
    boff[nf] = (wc * 32 + nf * 16 + c) * 40 + r * 8;

  for (int m0 = 0; m0 < nrows; m0 += 256) {
    const unsigned short *ga0, *ga1;
    {
      int r0 = min(m0 + am, nrows - 1), r1 = min(m0 + 128 + am, nrows - 1);
      int t0 = offp ? tok[rowbase + r0] : (rowbase + r0);
      int t1 = offp ? tok[rowbase + r1] : (rowbase + r1);
      ga0 = xb + (size_t)t0 * K + kksw * 8;
      ga1 = xb + (size_t)t1 * K + kksw * 8;
    }

    floatx4 accg[4][2] = {};
    floatx4 accu[4][2] = {};
    float4 bg1, bu1, bg2, bu2;

    // prologue
    {
      float4 a = *(const float4*)gsrc;
      float4 b = *(const float4*)usrc;
      SCHED0;
      gld_lds16(ga0, &As[0][tid * 8]);
      gld_lds16(ga1, &As[0][4096 + tid * 8]);
      SCHED0;
      bg1 = *(const float4*)(gsrc + (size_t)32 * N);
      bu1 = *(const float4*)(usrc + (size_t)32 * N);
      SCHED0;
      uint2 og = xpose_b(a, r), ou = xpose_b(b, r);
      *(uint2*)&Bg[0][bwoff] = og;
      *(uint2*)&Bu[0][bwoff] = ou;
    }
    LGKM0;
    asm volatile("s_waitcnt vmcnt(2)" ::: "memory");
    SBAR; SCHED0;

    for (int kt = 0; kt < NK; kt += 2) {
      // ---------- even step: compute buf 0 ----------
      {
        bool hl = (kt + 2 < NK);
        gld_lds16(ga0 + (kt + 1) * 32, &As[1][tid * 8]);
        gld_lds16(ga1 + (kt + 1) * 32, &As[1][4096 + tid * 8]);
        SCHED0;
        if (hl) {
          bg2 = *(const float4*)(gsrc + (size_t)(kt + 2) * 32 * N);
          bu2 = *(const float4*)(usrc + (size_t)(kt + 2) * 32 * N);
        }
        SCHED0;
        {
          uint2 og = xpose_b(bg1, r), ou = xpose_b(bu1, r);
          *(uint2*)&Bg[1][bwoff] = og;
          *(uint2*)&Bu[1][bwoff] = ou;
        }
        short8 af[4];
        #pragma unroll
        for (int mf = 0; mf < 4; ++mf) af[mf] = *(const short8*)&As[0][aoff[mf]];
        #pragma unroll
        for (int nf = 0; nf < 2; ++nf) {
          short8 fg = *(const short8*)&Bg[0][boff[nf]];
          short8 fu = *(const short8*)&Bu[0][boff[nf]];
          #pragma unroll
          for (int mf = 0; mf < 4; ++mf) {
            accg[mf][nf] = __builtin_amdgcn_mfma_f32_16x16x32_bf16(af[mf], fg, accg[mf][nf], 0, 0, 0);
            accu[mf][nf] = __builtin_amdgcn_mfma_f32_16x16x32_bf16(af[mf], fu, accu[mf][nf], 0, 0, 0);
          }
        }
        LGKM0;
        if (hl) asm volatile("s_waitcnt vmcnt(2)" ::: "memory");
        else    asm volatile("s_waitcnt vmcnt(0)" ::: "memory");
        SBAR; SCHED0;
      }
      // ---------- odd step: compute buf 1 ----------
      {
        int k1 = kt + 1;
        bool hl = (k1 + 2 < NK), hu = (k1 + 1 < NK);
        if (hu) {
          gld_lds16(ga0 + (k1 + 1) * 32, &As[0][tid * 8]);
          gld_lds16(ga1 + (k1 + 1) * 32, &As[0][4096 + tid * 8]);
        }
        SCHED0;
        if (hl) {
          bg1 = *(const float4*)(gsrc + (size_t)(k1 + 2) * 32 * N);
          bu1 = *(const float4*)(usrc + (size_t)(k1 + 2) * 32 * N);
        }
        SCHED0;
        if (hu) {
          uint2 og = xpose_b(bg2, r), ou = xpose_b(bu2, r);
          *(uint2*)&Bg[0][bwoff] = og;
          *(uint2*)&Bu[0][bwoff] = ou;
        }
        short8 af[4];
        #pragma unroll
        for (int mf = 0; mf < 4; ++mf) af[mf] = *(const short8*)&As[1][aoff[mf]];
        #pragma unroll
        for (int nf = 0; nf < 2; ++nf) {
          short8 fg = *(const short8*)&Bg[1][boff[nf]];
          short8 fu = *(const short8*)&Bu[1][boff[nf]];
          #pragma unroll
          for (int mf = 0; mf < 4; ++mf) {
            accg[mf][nf] = __builtin_amdgcn_mfma_f32_16x16x32_bf16(af[mf], fg, accg[mf][nf], 0, 0, 0);
            accu[mf][nf] = __builtin_amdgcn_mfma_f32_16x16x32_bf16(af[mf], fu, accu[mf][nf], 0, 0, 0);
          }
        }
        LGKM0;
        if (hl) asm volatile("s_waitcnt vmcnt(2)" ::: "memory");
        else    asm volatile("s_waitcnt vmcnt(0)" ::: "memory");
        SBAR; SCHED0;
      }
    }

    // epilogue: silu(g)*u -> bf16
    #pragma unroll
    for (int mf = 0; mf < 4; ++mf)
      #pragma unroll
      for (int nf = 0; nf < 2; ++nf)
        #pragma unroll
        for (int v = 0; v < 4; ++v) {
          int rr = wr * 64 + mf * 16 + r * 4 + v;
          if (m0 + rr < nrows) {
            float g = accg[mf][nf][v], u = accu[mf][nf][v];
            float s = g / (1.f + __expf(-g));
            hout[(size_t)(rowbase + m0 + rr) * N + n0 + wc * 32 + nf * 16 + c] = f2b(s * u);
          }
        }
  }
}

// =================================================================
// Down-proj grouped GEMM: same pipeline, single B matrix.
// Routed: atomicAdd(w*scale*acc) scattered by token.  Dense: plain store.
// =================================================================
__global__ __launch_bounds__(512, 4) void k_down3(
    const unsigned short* __restrict__ hin,
    const float* __restrict__ wd_base,
    const int* __restrict__ offp, const int* __restrict__ cnt,
    const int* __restrict__ tok, const float* __restrict__ wts,
    float* __restrict__ out, int N, int K, float scale)
{
  __shared__ __align__(16) unsigned short As[2][8192];
  __shared__ __align__(16) unsigned short Bd[2][64 * 40];

  const int tid = threadIdx.x;
  const int wid = tid >> 6, lane = tid & 63;
  const int c = lane & 15, r = lane >> 4;
  const int n0 = blockIdx.x * 64;

  int e, rowbase, nrows;
  if (offp) { e = blockIdx.y; rowbase = offp[e]; nrows = cnt[e]; }
  else      { e = 0; rowbase = blockIdx.y * 256; nrows = 256; }
  if (nrows <= 0) return;

  const float* dsrc = wd_base + (size_t)e * K * N + (size_t)(wid * 4 + r) * N + n0 + c * 4;
  const int bwoff = (4 * c + r) * 40 + wid * 4;

  const int am = tid >> 2;
  const int kksw = (tid & 3) ^ ((tid >> 3) & 3);
  const int NK = K >> 5;

  const int wr = wid >> 1, wc = wid & 1;
  int aoff[4];
  #pragma unroll
  for (int mf = 0; mf < 4; ++mf) {
    int m = wr * 64 + mf * 16 + c;
    aoff[mf] = (m * 4 + (r ^ ((m >> 1) & 3))) * 8;
  }
  int boff[2];
  #pragma unroll
  for (int nf = 0; nf < 2; ++nf)
    boff[nf] = (wc * 32 + nf * 16 + c) * 40 + r * 8;

  for (int m0 = 0; m0 < nrows; m0 += 256) {
    const unsigned short *ga0, *ga1;
    {
      int r0 = min(m0 + am, nrows - 1), r1 = min(m0 + 128 + am, nrows - 1);
      ga0 = hin + (size_t)(rowbase + r0) * K + kksw * 8;
      ga1 = hin + (size_t)(rowbase + r1) * K + kksw * 8;
    }

    floatx4 acc[4][2] = {};
    float4 bd1, bd2;

    {
      float4 a = *(const float4*)dsrc;
      SCHED0;
      gld_lds16(ga0, &As[0][tid * 8]);
      gld_lds16(ga1, &As[0][4096 + tid * 8]);
      SCHED0;
      bd1 = *(const float4*)(dsrc + (size_t)32 * N);
      SCHED0;
      uint2 od = xpose_b(a, r);
      *(uint2*)&Bd[0][bwoff] = od;
    }
    LGKM0;
    asm volatile("s_waitcnt vmcnt(1)" ::: "memory");
    SBAR; SCHED0;

    for (int kt = 0; kt < NK; kt += 2) {
      // even
      {
        bool hl = (kt + 2 < NK);
        gld_lds16(ga0 + (kt + 1) * 32, &As[1][tid * 8]);
        gld_lds16(ga1 + (kt + 1) * 32, &As[1][4096 + tid * 8]);
        SCHED0;
        if (hl) bd2 = *(const float4*)(dsrc + (size_t)(kt + 2) * 32 * N);
        SCHED0;
        {
          uint2 od = xpose_b(bd1, r);
          *(uint2*)&Bd[1][bwoff] = od;
        }
        short8 af[4];
        #pragma unroll
        for (int mf = 0; mf < 4; ++mf) af[mf] = *(const short8*)&As[0][aoff[mf]];
        #pragma unroll
        for (int nf = 0; nf < 2; ++nf) {
          short8 fd = *(const short8*)&Bd[0][boff[nf]];
          #pragma unroll
          for (int mf = 0; mf < 4; ++mf)
            acc[mf][nf] = __builtin_amdgcn_mfma_f32_16x16x32_bf16(af[mf], fd, acc[mf][nf], 0, 0, 0);
        }
        LGKM0;
        if (hl) asm volatile("s_waitcnt vmcnt(1)" ::: "memory");
        else    asm volatile("s_waitcnt vmcnt(0)" ::: "memory");
        SBAR; SCHED0;
      }
      // odd
      {
        int k1 = kt + 1;
        bool hl = (k1 + 2 < NK), hu = (k1 + 1 < NK);
        if (hu) {
          gld_lds16(ga0 + (k1 + 1) * 32, &As[0][tid * 8]);
          gld_lds16(ga1 + (k1 + 1) * 32, &As[0][4096 + tid * 8]);
        }
        SCHED0;
        if (hl) bd1 = *(const float4*)(dsrc + (size_t)(k1 + 2) * 32 * N);
        SCHED0;
        if (hu) {
          uint2 od = xpose_b(bd2, r);
          *(uint2*)&Bd[0][bwoff] = od;
        }
        short8 af[4];
        #pragma unroll
        for (int mf = 0; mf < 4; ++mf) af[mf] = *(const short8*)&As[1][aoff[mf]];
        #pragma unroll
        for (int nf = 0; nf < 2; ++nf) {
          short8 fd = *(const short8*)&Bd[1][boff[nf]];
          #pragma unroll
          for (int mf = 0; mf < 4; ++mf)
            acc[mf][nf] = __builtin_amdgcn_mfma_f32_16x16x32_bf16(af[mf], fd, acc[mf][nf], 0, 0, 0);
        }
        LGKM0;
        if (hl) asm volatile("s_waitcnt vmcnt(1)" ::: "memory");
        else    asm volatile("s_waitcnt vmcnt(0)" ::: "memory");
        SBAR; SCHED0;
      }
    }

    #pragma unroll
    for (int mf = 0; mf < 4; ++mf)
      #pragma unroll
      for (int nf = 0; nf < 2; ++nf)
        #pragma unroll
        for (int v = 0; v < 4; ++v) {
          int rr = wr * 64 + mf * 16 + r * 4 + v;
          if (m0 + rr < nrows) {
            int grow = rowbase + m0 + rr;
            int col = n0 + wc * 32 + nf * 16 + c;
            if (offp) {
              float w = wts[grow] * scale;
              atomicAdd(&out[(size_t)tok[grow] * N + col], w * acc[mf][nf][v]);
            } else {
              out[(size_t)grow * N + col] = acc[mf][nf][v] * scale;
            }
          }
        }
  }
}

extern "C" void kernel_launch(void* const* d_in, const int* in_sizes, int n_in,
                              void* d_out, int out_size, void* d_ws, size_t ws_size,
                              hipStream_t stream) {
  const float* x    = (const float*)d_in[0];
  const float* gw   = (const float*)d_in[1];
  const float* bias = (const float*)d_in[2];
  const float* wg   = (const float*)d_in[3];
  const float* wu   = (const float*)d_in[4];
  const float* wd   = (const float*)d_in[5];
  const float* wsg  = (const float*)d_in[6];
  const float* wsu  = (const float*)d_in[7];
  const float* wsd  = (const float*)d_in[8];
  float* out = (float*)d_out;

  char* ws = (char*)d_ws;
  size_t o = 0;
  auto take = [&](size_t bytes) {
    char* p = ws + o;
    o += (bytes + 255) & ~(size_t)255;
    return p;
  };
  int*   tki  = (int*)  take((size_t)T_TOK * TOPK * 4);
  float* tkw  = (float*)take((size_t)T_TOK * TOPK * 4);
  int*   cnt  = (int*)  take(NEXP * 4);
  int*   offp = (int*)  take((NEXP + 1) * 4);
  int*   tok  = (int*)  take((size_t)T_TOK * TOPK * 4);
  float* wts  = (float*)take((size_t)T_TOK * TOPK * 4);
  unsigned short* xb = (unsigned short*)take((size_t)T_TOK * D_HID * 2);
  unsigned short* hb = (unsigned short*)take((size_t)T_TOK * TOPK * I_EXP * 2);
  unsigned short* sh = (unsigned short*)take((size_t)T_TOK * SHI * 2);

  k_route<<<T_TOK, 64, 0, stream>>>(x, gw, bias, tki, tkw);
  k_count<<<1, 256, 0, stream>>>(tki, cnt, offp);
  k_compact<<<NEXP, 64, 0, stream>>>(tki, tkw, offp, tok, wts);
  k_cast<<<(T_TOK * D_HID / 4 + 255) / 256, 256, 0, stream>>>(x, xb, T_TOK * D_HID / 4);

  // shared expert gate+up (dense, 4 m-chunks)
  k_gateup3<<<dim3(SHI / 64, T_TOK / 256), 512, 0, stream>>>(
      xb, wsg, wsu, nullptr, nullptr, nullptr, sh, SHI, D_HID);
  // routed gate+up (grouped)
  k_gateup3<<<dim3(I_EXP / 64, NEXP), 512, 0, stream>>>(
      xb, wg, wu, offp, cnt, tok, hb, I_EXP, D_HID);
  // shared down: plain store (initializes out)
  k_down3<<<dim3(D_HID / 64, T_TOK / 256), 512, 0, stream>>>(
      sh, wsd, nullptr, nullptr, nullptr, nullptr, out, D_HID, SHI, 1.0f);
  // routed down: atomic accumulate on top
  k_down3<<<dim3(D_HID / 64, NEXP), 512, 0, stream>>>(
      hb, wd, offp, cnt, tok, wts, out, D_HID, I_EXP, RSCALE);
}